// Round 3
// baseline (593.369 us; speedup 1.0000x reference)
//
#include <hip/hip_runtime.h>
#include <math.h>
#include <stdint.h>

#define T_   512
#define H_   1024
#define I_   512
#define E_   64
#define K_   6
#define G_   8
#define TG_  3
#define EB_  80      // 64 routed + 16 shared-expert (half x token-eighth) blocks

typedef _Float16 h8 __attribute__((ext_vector_type(8)));
typedef _Float16 h4v __attribute__((ext_vector_type(4)));
typedef float    f4 __attribute__((ext_vector_type(4)));

// ---------------- router: sigmoid + group-limited top-k (verified) ------
__global__ __launch_bounds__(64) void router_k(
    const float* __restrict__ x, const float* __restrict__ gw,
    int* __restrict__ cnt, int* __restrict__ tlist, float* __restrict__ wlist)
{
  const int t   = blockIdx.x;
  const int tid = threadIdx.x;
  __shared__ float sx[H_];
  __shared__ float sc[E_];

  for (int h4 = tid; h4 < H_/4; h4 += 64)
    ((float4*)sx)[h4] = ((const float4*)(x + (size_t)t*H_))[h4];
  __syncthreads();

  const float* wr = gw + (size_t)tid * H_;
  float acc = 0.f;
  for (int h = 0; h < H_; h += 4) {
    float4 xv = *(const float4*)(sx + h);
    float4 wv = *(const float4*)(wr + h);
    acc = fmaf(xv.x, wv.x, acc); acc = fmaf(xv.y, wv.y, acc);
    acc = fmaf(xv.z, wv.z, acc); acc = fmaf(xv.w, wv.w, acc);
  }
  sc[tid] = 1.f / (1.f + expf(-acc));
  __syncthreads();

  if (tid == 0) {
    float gs[G_];
    #pragma unroll
    for (int g = 0; g < G_; g++) {
      float m = sc[g*8];
      #pragma unroll
      for (int j = 1; j < 8; j++) m = fmaxf(m, sc[g*8+j]);
      gs[g] = m;
    }
    unsigned gp = 0;
    for (int r = 0; r < TG_; r++) {
      int best = 0; float bv = -1e30f;
      for (int g = 0; g < G_; g++)
        if (!((gp >> g) & 1) && gs[g] > bv) { bv = gs[g]; best = g; }
      gp |= 1u << best;
    }
    int   eidx[K_]; float ew[K_];
    unsigned long long em = 0ull;
    float wsum = 0.f;
    for (int r = 0; r < K_; r++) {
      int best = 0; float bv = -1e30f;
      for (int e = 0; e < E_; e++) {
        if (!((gp >> (e >> 3)) & 1)) continue;
        if ((em >> e) & 1ull) continue;
        if (sc[e] > bv) { bv = sc[e]; best = e; }
      }
      em |= 1ull << best; eidx[r] = best; ew[r] = bv; wsum += bv;
    }
    const float inv = 2.5f / (wsum + 1e-20f);
    for (int r = 0; r < K_; r++) {
      int e = eidx[r];
      int pos = atomicAdd(&cnt[e], 1);
      tlist[e*T_ + pos] = (t << 13) | (t*K_ + r);   // hmid row = t*6+rank
      wlist[e*T_ + pos] = ew[r] * inv;
    }
  }
}

// ---------------- pseudo-expert token lists (shared halves) -------------
__global__ void pseudo_init_k(int* cnt, int* tlist, float* wlist) {
  int s = blockIdx.x*256 + threadIdx.x;       // 0..1023
  if (s == 0) { cnt[64] = T_; cnt[65] = T_; }
  if (s < 1024) {
    int e = 64 + (s >> 9);
    int t = s & 511;
    tlist[e*T_ + t] = (t << 13) | (3072 + s); // rows 3072..4095
    wlist[e*T_ + t] = 1.0f;
  }
}

// ---------------- x -> f16 prep ----------------------------------------
__global__ __launch_bounds__(256) void xh_prep_k(
    const float* __restrict__ x, _Float16* __restrict__ xh)
{
  int i = blockIdx.x*256 + threadIdx.x;       // float4 index
  float4 v = ((const float4*)x)[i];
  h4v o = { (_Float16)v.x, (_Float16)v.y, (_Float16)v.z, (_Float16)v.w };
  *(h4v*)(xh + (size_t)i*4) = o;
}

// ---- expert-block descriptor: eb<64 -> routed; eb>=64 -> shared slice ---
__device__ __forceinline__ void eb_decode(int eb, const int* cnt,
                                          int& e, int& lo, int& hi) {
  if (eb < E_) { e = eb; lo = 0; hi = cnt[e]; }
  else { int q = (eb - E_) & 7; e = E_ + ((eb - E_) >> 3); lo = q*64; hi = lo + 64; }
}

// 8 int32 weights (exact small ints) -> f16 fragment, NO scale
// (scale is folded into the f32 accumulator per 128-K block: more accurate)
__device__ __forceinline__ h8 cvt8i(int4 a, int4 b) {
  union { _Float16 f[8]; h8 v; } t;
  t.f[0]=(_Float16)a.x; t.f[1]=(_Float16)a.y; t.f[2]=(_Float16)a.z; t.f[3]=(_Float16)a.w;
  t.f[4]=(_Float16)b.x; t.f[5]=(_Float16)b.y; t.f[6]=(_Float16)b.z; t.f[7]=(_Float16)b.w;
  return t.v;
}

// ---------------- gate+up MFMA: hmid[row, ic*16..+16) -------------------
// Occupancy-first redesign: block tile = 16 i-rows, grid 32x80 = 2560 blocks,
// 6 blocks/CU (launch_bounds) -> ~24 resident waves/CU (vs 10 before).
// 4 waves share one staged f16 weight tile; wave wv computes M-subtile wv
// (16 tokens). Reg-staged W (2 int4/step/wave) -> cvt once -> ds_write_b128
// into padded [row][72] f16 tile (144B stride: conflict-free b128 r/w).
// 3-deep W/A reg rings, counted vmcnt(6) (never 0 mid-loop), 1 barrier/step.
#define NKT_G 16

#define GU_STEP(KT, WN)                                                       \
  do {                                                                        \
    asm volatile("s_waitcnt vmcnt(" #WN ") lgkmcnt(0)" ::: "memory");         \
    __builtin_amdgcn_sched_barrier(0);                                        \
    __builtin_amdgcn_s_barrier();                                             \
    if ((KT) + 1 < NKT_G)                                                     \
      *(h8*)(wdst + (((KT)+1)&1)*4608) =                                      \
          cvt8i(Wr[((KT)+1)%3][0], Wr[((KT)+1)%3][1]);                        \
    if ((KT) + 3 < NKT_G) {                                                   \
      Wr[((KT)+3)%3][0] = *(const int4*)(wsrc + ((KT)+3)*64);                 \
      Wr[((KT)+3)%3][1] = *(const int4*)(wsrc + ((KT)+3)*64 + 4);             \
    }                                                                         \
    {                                                                         \
      const char* tb = tb0 + (((KT)&1))*4608;                                 \
      h8 bg0 = *(const h8*)(tb);                                              \
      h8 bg1 = *(const h8*)(tb + 64);                                         \
      h8 bu0 = *(const h8*)(tb + 2304);                                       \
      h8 bu1 = *(const h8*)(tb + 2304 + 64);                                  \
      if (((KT)&1) == 0) { partg = (f4){0.f,0.f,0.f,0.f}; partu = partg; }    \
      partg = __builtin_amdgcn_mfma_f32_16x16x32_f16(Ar[(KT)%3][0], bg0, partg, 0,0,0); \
      partg = __builtin_amdgcn_mfma_f32_16x16x32_f16(Ar[(KT)%3][1], bg1, partg, 0,0,0); \
      partu = __builtin_amdgcn_mfma_f32_16x16x32_f16(Ar[(KT)%3][0], bu0, partu, 0,0,0); \
      partu = __builtin_amdgcn_mfma_f32_16x16x32_f16(Ar[(KT)%3][1], bu1, partu, 0,0,0); \
      if (((KT)&1) == 1) {                                                    \
        totg += partg * sgv[(KT)>>1];                                         \
        totu += partu * suv[(KT)>>1];                                         \
      }                                                                       \
    }                                                                         \
    if ((KT) + 3 < NKT_G) {                                                   \
      Ar[((KT)+3)%3][0] = *(const h8*)(ax + ((KT)+3)*64);                     \
      Ar[((KT)+3)%3][1] = *(const h8*)(ax + ((KT)+3)*64 + 32);                \
    }                                                                         \
  } while (0)

__global__ __launch_bounds__(256, 6) void gateup_k(
    const _Float16* __restrict__ xh,
    const int* __restrict__ wg, const float* __restrict__ sg,
    const int* __restrict__ wu, const float* __restrict__ su,
    const int* __restrict__ shwg, const float* __restrict__ shsg,
    const int* __restrict__ shwu, const float* __restrict__ shsu,
    const int* __restrict__ cnt, const int* __restrict__ tlist,
    const float* __restrict__ wlist,
    _Float16* __restrict__ hmid)
{
  const int ic = blockIdx.x;                  // i-chunk of 16 (0..31)
  const int eb = blockIdx.y;
  int e, lo, hi;
  eb_decode(eb, cnt, e, lo, hi);
  if (hi <= lo) return;

  const int tid  = threadIdx.x;
  const int lane = tid & 63;
  const int wv   = tid >> 6;
  const int mr   = lane & 15;
  const int quad = lane >> 4;

  const int *wgb, *wub; const float *sgp, *sup; int sib;
  if (e < E_) {
    wgb = wg + (size_t)e*I_*H_;  wub = wu + (size_t)e*I_*H_;
    sgp = sg + e*32;  sup = su + e*32;  sib = ic >> 3;
  } else {
    int hf = e - E_;
    wgb = shwg + (size_t)hf*512*H_;  wub = shwu + (size_t)hf*512*H_;
    sgp = shsg;  sup = shsu;  sib = hf*4 + (ic >> 3);
  }
  float sgv[8], suv[8];
  #pragma unroll
  for (int b = 0; b < 8; b++) { sgv[b] = sgp[sib*8+b]; suv[b] = sup[sib*8+b]; }

  __shared__ _Float16 tile[2][2][16][72];     // [buf][mat][row][64k + 8 pad]
  __shared__ int stok[64]; __shared__ int srw[64]; __shared__ float swt[64];
  char* tilebytes = (char*)&tile[0][0][0][0];

  // staging role: wave -> (mat, 8-row half); lane -> (row, 8-int chunk)
  const int smat = wv >> 1;
  const int srow = (wv & 1)*8 + (lane >> 3);
  const int* wsrc = (smat ? wub : wgb) + (size_t)(ic*16 + srow)*H_ + (lane & 7)*8;
  char* wdst = tilebytes + smat*2304 + srow*144 + (lane & 7)*16;
  const char* tb0 = tilebytes + mr*144 + quad*16;

  int4 Wr[3][2];
  h8   Ar[3][2];

  for (int base = lo; base < hi; base += 64) {
    __syncthreads();
    if (tid < 64) {
      int slot = base + tid;
      if (slot < hi) {
        int ent = tlist[e*T_ + slot];
        stok[tid] = ent >> 13; srw[tid] = ent & 8191; swt[tid] = wlist[e*T_ + slot];
      } else { stok[tid] = -1; srw[tid] = 0; swt[tid] = 0.f; }
    }
    __syncthreads();

    int tk = stok[wv*16 + mr]; if (tk < 0) tk = 0;
    const _Float16* ax = xh + (size_t)tk*H_ + quad*8;

    f4 totg = (f4){0.f,0.f,0.f,0.f}, totu = totg, partg = totg, partu = totg;

    // prologue: W0 A0 W1 A1 W2 A2, then write tile0
    Wr[0][0] = *(const int4*)(wsrc);       Wr[0][1] = *(const int4*)(wsrc + 4);
    Ar[0][0] = *(const h8*)(ax);           Ar[0][1] = *(const h8*)(ax + 32);
    Wr[1][0] = *(const int4*)(wsrc + 64);  Wr[1][1] = *(const int4*)(wsrc + 68);
    Ar[1][0] = *(const h8*)(ax + 64);      Ar[1][1] = *(const h8*)(ax + 96);
    Wr[2][0] = *(const int4*)(wsrc + 128); Wr[2][1] = *(const int4*)(wsrc + 132);
    Ar[2][0] = *(const h8*)(ax + 128);     Ar[2][1] = *(const h8*)(ax + 160);
    *(h8*)(wdst) = cvt8i(Wr[0][0], Wr[0][1]);

    GU_STEP(0,6);  GU_STEP(1,6);  GU_STEP(2,6);  GU_STEP(3,6);
    GU_STEP(4,6);  GU_STEP(5,6);  GU_STEP(6,6);  GU_STEP(7,6);
    GU_STEP(8,6);  GU_STEP(9,6);  GU_STEP(10,6); GU_STEP(11,6);
    GU_STEP(12,6); GU_STEP(13,6); GU_STEP(14,2); GU_STEP(15,0);

    // epilogue: silu(g)*u*w -> hmid  (C/D: col=mr (i), row=quad*4+r (token))
    const int icol = ic*16 + mr;
    #pragma unroll
    for (int r = 0; r < 4; r++) {
      int sl = wv*16 + quad*4 + r;
      if (stok[sl] >= 0) {
        float g = totg[r];
        float m = g / (1.f + expf(-g)) * totu[r] * swt[sl];
        hmid[(size_t)srw[sl]*I_ + icol] = (_Float16)m;
      }
    }
  }
}
#undef GU_STEP

// ---------------- down MFMA: scr[t*8+rank, hc*32..+32) = hmid @ Wd ------
// Same occupancy-first structure: 32 h-cols/block, grid 32x80 = 2560 blocks.
// Reg-staged TRANSPOSED write: lane loads 4 i-rows x 2 h-cols (4x int2,
// coalesced 128B/row), writes 2x h4v (4 i-contig f16) into [32h][72] tile.
#define NKT_D 8

#define DN_LDW(S, KT)                                                         \
  do {                                                                        \
    Wr[S][0] = *(const int2*)(dsrc + (size_t)((KT)*64 + 0)*H_);               \
    Wr[S][1] = *(const int2*)(dsrc + (size_t)((KT)*64 + 1)*H_);               \
    Wr[S][2] = *(const int2*)(dsrc + (size_t)((KT)*64 + 2)*H_);               \
    Wr[S][3] = *(const int2*)(dsrc + (size_t)((KT)*64 + 3)*H_);               \
  } while (0)

#define DN_WRITE(S, BUF)                                                      \
  do {                                                                        \
    union { _Float16 f[4]; h4v v; } v0, v1;                                   \
    v0.f[0]=(_Float16)Wr[S][0].x; v0.f[1]=(_Float16)Wr[S][1].x;               \
    v0.f[2]=(_Float16)Wr[S][2].x; v0.f[3]=(_Float16)Wr[S][3].x;               \
    v1.f[0]=(_Float16)Wr[S][0].y; v1.f[1]=(_Float16)Wr[S][1].y;               \
    v1.f[2]=(_Float16)Wr[S][2].y; v1.f[3]=(_Float16)Wr[S][3].y;               \
    *(h4v*)(ddst + (BUF)*4608)       = v0.v;                                  \
    *(h4v*)(ddst + (BUF)*4608 + 144) = v1.v;                                  \
  } while (0)

#define DN_STEP(KT, WN)                                                       \
  do {                                                                        \
    asm volatile("s_waitcnt vmcnt(" #WN ") lgkmcnt(0)" ::: "memory");         \
    __builtin_amdgcn_sched_barrier(0);                                        \
    __builtin_amdgcn_s_barrier();                                             \
    if ((KT) + 1 < NKT_D) DN_WRITE(((KT)+1)%3, ((KT)+1)&1);                   \
    if ((KT) + 3 < NKT_D) DN_LDW(((KT)+3)%3, (KT)+3);                         \
    {                                                                         \
      const char* tb = tb0 + (((KT)&1))*4608;                                 \
      h8 b00 = *(const h8*)(tb);                                              \
      h8 b01 = *(const h8*)(tb + 64);                                         \
      h8 b10 = *(const h8*)(tb + 2304);                                       \
      h8 b11 = *(const h8*)(tb + 2304 + 64);                                  \
      if (((KT)&1) == 0) { part0 = (f4){0.f,0.f,0.f,0.f}; part1 = part0; }    \
      part0 = __builtin_amdgcn_mfma_f32_16x16x32_f16(Ar[(KT)%3][0], b00, part0, 0,0,0); \
      part0 = __builtin_amdgcn_mfma_f32_16x16x32_f16(Ar[(KT)%3][1], b01, part0, 0,0,0); \
      part1 = __builtin_amdgcn_mfma_f32_16x16x32_f16(Ar[(KT)%3][0], b10, part1, 0,0,0); \
      part1 = __builtin_amdgcn_mfma_f32_16x16x32_f16(Ar[(KT)%3][1], b11, part1, 0,0,0); \
      if (((KT)&1) == 1) {                                                    \
        tot0 += part0 * sdv[(KT)>>1];                                         \
        tot1 += part1 * sdv[(KT)>>1];                                         \
      }                                                                       \
    }                                                                         \
    if ((KT) + 3 < NKT_D) {                                                   \
      Ar[((KT)+3)%3][0] = *(const h8*)(ap + ((KT)+3)*64);                     \
      Ar[((KT)+3)%3][1] = *(const h8*)(ap + ((KT)+3)*64 + 32);                \
    }                                                                         \
  } while (0)

__global__ __launch_bounds__(256, 6) void down_k(
    const int* __restrict__ wd, const float* __restrict__ sd,
    const int* __restrict__ shwd, const float* __restrict__ shsd,
    const int* __restrict__ cnt, const int* __restrict__ tlist,
    const _Float16* __restrict__ hmid, float* __restrict__ scr)
{
  const int hc = blockIdx.x;                  // h-chunk of 32 (0..31)
  const int eb = blockIdx.y;
  int e, lo, hi;
  eb_decode(eb, cnt, e, lo, hi);
  if (hi <= lo) return;

  const int tid  = threadIdx.x;
  const int lane = tid & 63;
  const int wv   = tid >> 6;
  const int mr   = lane & 15;
  const int quad = lane >> 4;

  const int* wb; const float* sdp; int sib0;
  if (e < E_) { wb = wd + (size_t)e*I_*H_;        sdp = sd + e*32;  sib0 = 0; }
  else { int hf = e - E_; wb = shwd + (size_t)hf*512*H_; sdp = shsd; sib0 = hf*4; }
  float sdv[4];
  #pragma unroll
  for (int ib = 0; ib < 4; ib++) sdv[ib] = sdp[(sib0+ib)*8 + (hc >> 2)];

  __shared__ _Float16 tile[2][32][72];        // [buf][h][64i + 8 pad]
  __shared__ int stok[64]; __shared__ int srw[64];
  char* tilebytes = (char*)&tile[0][0][0];

  const int rg = lane >> 4;
  const int* dsrc = wb + (size_t)(wv*16 + rg*4)*H_ + hc*32 + (lane & 15)*2;
  char* ddst = tilebytes + ((lane & 15)*2)*144 + (wv*16 + rg*4)*2;
  const char* tb0 = tilebytes + mr*144 + quad*16;   // nf=0; nf=1 at +2304

  int2 Wr[3][4];
  h8   Ar[3][2];

  for (int base = lo; base < hi; base += 64) {
    __syncthreads();
    if (tid < 64) {
      int slot = base + tid;
      if (slot < hi) {
        int ent = tlist[e*T_ + slot];
        stok[tid] = ent >> 13; srw[tid] = ent & 8191;
      } else { stok[tid] = -1; srw[tid] = 0; }
    }
    __syncthreads();

    const _Float16* ap = hmid + (size_t)srw[wv*16 + mr]*I_ + quad*8;

    f4 tot0 = (f4){0.f,0.f,0.f,0.f}, tot1 = tot0, part0 = tot0, part1 = tot0;

    DN_LDW(0, 0);
    Ar[0][0] = *(const h8*)(ap);        Ar[0][1] = *(const h8*)(ap + 32);
    DN_LDW(1, 1);
    Ar[1][0] = *(const h8*)(ap + 64);   Ar[1][1] = *(const h8*)(ap + 96);
    DN_LDW(2, 2);
    Ar[2][0] = *(const h8*)(ap + 128);  Ar[2][1] = *(const h8*)(ap + 160);
    DN_WRITE(0, 0);

    DN_STEP(0,6); DN_STEP(1,6); DN_STEP(2,6); DN_STEP(3,6);
    DN_STEP(4,6); DN_STEP(5,6); DN_STEP(6,2); DN_STEP(7,0);

    // epilogue: exactly-once stores to scr[(t*8+rank)][hcol]
    #pragma unroll
    for (int r = 0; r < 4; r++) {
      int sl = wv*16 + quad*4 + r;
      if (stok[sl] >= 0) {
        int t  = stok[sl];
        int sr = srw[sl];
        int rank = (sr < 3072) ? (sr - t*6) : (6 + ((sr - 3072) >> 9));
        float* dst = scr + (size_t)(t*8 + rank)*H_ + hc*32 + mr;
        dst[0]  = tot0[r];
        dst[16] = tot1[r];
      }
    }
  }
}
#undef DN_STEP
#undef DN_WRITE
#undef DN_LDW

// ---------------- combine: out[t,h] = sum_r scratch[t*8+r, h] -----------
__global__ __launch_bounds__(256) void combine_k(
    const float* __restrict__ scr, float* __restrict__ out)
{
  int i = blockIdx.x*256 + threadIdx.x;       // float4 index over T*H/4
  int t = i >> 8;                             // 256 float4 per token row
  int c = i & 255;
  const float4* base = (const float4*)(scr + (size_t)t*8*H_) + c;
  float4 s = base[0];
  #pragma unroll
  for (int r = 1; r < 8; r++) {
    float4 v = base[(size_t)r*(H_/4)];
    s.x += v.x; s.y += v.y; s.z += v.z; s.w += v.w;
  }
  ((float4*)out)[i] = s;
}

// ---------------- launch ----------------
extern "C" void kernel_launch(void* const* d_in, const int* in_sizes, int n_in,
                              void* d_out, int out_size, void* d_ws, size_t ws_size,
                              hipStream_t stream) {
  (void)in_sizes; (void)n_in; (void)ws_size; (void)out_size;
  const float* x    = (const float*)d_in[0];
  const float* gw   = (const float*)d_in[1];
  const int*   wg   = (const int*  )d_in[2];
  const float* sg   = (const float*)d_in[3];
  const int*   wu   = (const int*  )d_in[4];
  const float* su   = (const float*)d_in[5];
  const int*   wd   = (const int*  )d_in[6];
  const float* sd   = (const float*)d_in[7];
  const int*   shwg = (const int*  )d_in[8];
  const float* shsg = (const float*)d_in[9];
  const int*   shwu = (const int*  )d_in[10];
  const float* shsu = (const float*)d_in[11];
  const int*   shwd = (const int*  )d_in[12];
  const float* shsd = (const float*)d_in[13];
  float* out = (float*)d_out;

  char* ws = (char*)d_ws;
  int*      cnt   = (int*     ) ws;                                   // 66 ints
  int*      tlist = (int*     )(ws + 1024);                           // 66*512
  float*    wlist = (float*   )(ws + 1024 + 66*T_*4);                 // 66*512
  _Float16* hmid  = (_Float16*)(ws + 1024 + 2*66*T_*4);               // 4096*512 f16
  _Float16* xh    = (_Float16*)(ws + 1024 + 2*66*T_*4 + 4096*I_*2);   // 512*1024 f16
  float*    scr   = (float*   )(ws + 1024 + 2*66*T_*4 + 4096*I_*2 + T_*H_*2); // 4096*1024 f32

  hipMemsetAsync(cnt, 0, 1024, stream);
  xh_prep_k<<<T_*H_/1024, 256, 0, stream>>>(x, xh);
  router_k<<<T_, 64, 0, stream>>>(x, gw, cnt, tlist, wlist);
  pseudo_init_k<<<4, 256, 0, stream>>>(cnt, tlist, wlist);
  gateup_k<<<dim3(32, EB_), 256, 0, stream>>>(xh, wg, sg, wu, su,
                                              shwg, shsg, shwu, shsu,
                                              cnt, tlist, wlist, hmid);
  down_k<<<dim3(32, EB_), 256, 0, stream>>>(wd, sd, shwd, shsd,
                                            cnt, tlist, hmid, scr);
  combine_k<<<T_*H_/1024, 256, 0, stream>>>(scr, out);
}

// Round 4
// 557.301 us; speedup vs baseline: 1.0647x; 1.0647x over previous
//
#include <hip/hip_runtime.h>
#include <math.h>
#include <stdint.h>

#define T_   512
#define H_   1024
#define I_   512
#define E_   64
#define K_   6
#define G_   8
#define TG_  3
#define EB_  80      // 64 routed + 16 shared-expert (half x token-eighth) blocks

typedef _Float16 h8 __attribute__((ext_vector_type(8)));
typedef _Float16 h4v __attribute__((ext_vector_type(4)));
typedef float    f4 __attribute__((ext_vector_type(4)));

// ---------------- router: sigmoid + group-limited top-k (verified) ------
__global__ __launch_bounds__(64) void router_k(
    const float* __restrict__ x, const float* __restrict__ gw,
    int* __restrict__ cnt, int* __restrict__ tlist, float* __restrict__ wlist)
{
  const int t   = blockIdx.x;
  const int tid = threadIdx.x;
  __shared__ float sx[H_];
  __shared__ float sc[E_];

  for (int h4 = tid; h4 < H_/4; h4 += 64)
    ((float4*)sx)[h4] = ((const float4*)(x + (size_t)t*H_))[h4];
  __syncthreads();

  const float* wr = gw + (size_t)tid * H_;
  float acc = 0.f;
  for (int h = 0; h < H_; h += 4) {
    float4 xv = *(const float4*)(sx + h);
    float4 wv = *(const float4*)(wr + h);
    acc = fmaf(xv.x, wv.x, acc); acc = fmaf(xv.y, wv.y, acc);
    acc = fmaf(xv.z, wv.z, acc); acc = fmaf(xv.w, wv.w, acc);
  }
  sc[tid] = 1.f / (1.f + expf(-acc));
  __syncthreads();

  if (tid == 0) {
    float gs[G_];
    #pragma unroll
    for (int g = 0; g < G_; g++) {
      float m = sc[g*8];
      #pragma unroll
      for (int j = 1; j < 8; j++) m = fmaxf(m, sc[g*8+j]);
      gs[g] = m;
    }
    unsigned gp = 0;
    for (int r = 0; r < TG_; r++) {
      int best = 0; float bv = -1e30f;
      for (int g = 0; g < G_; g++)
        if (!((gp >> g) & 1) && gs[g] > bv) { bv = gs[g]; best = g; }
      gp |= 1u << best;
    }
    int   eidx[K_]; float ew[K_];
    unsigned long long em = 0ull;
    float wsum = 0.f;
    for (int r = 0; r < K_; r++) {
      int best = 0; float bv = -1e30f;
      for (int e = 0; e < E_; e++) {
        if (!((gp >> (e >> 3)) & 1)) continue;
        if ((em >> e) & 1ull) continue;
        if (sc[e] > bv) { bv = sc[e]; best = e; }
      }
      em |= 1ull << best; eidx[r] = best; ew[r] = bv; wsum += bv;
    }
    const float inv = 2.5f / (wsum + 1e-20f);
    for (int r = 0; r < K_; r++) {
      int e = eidx[r];
      int pos = atomicAdd(&cnt[e], 1);
      tlist[e*T_ + pos] = (t << 13) | (t*K_ + r);   // hmid row = t*6+rank
      wlist[e*T_ + pos] = ew[r] * inv;
    }
  }
}

// ---------------- pseudo-expert token lists (shared halves) -------------
__global__ void pseudo_init_k(int* cnt, int* tlist, float* wlist) {
  int s = blockIdx.x*256 + threadIdx.x;       // 0..1023
  if (s == 0) { cnt[64] = T_; cnt[65] = T_; }
  if (s < 1024) {
    int e = 64 + (s >> 9);
    int t = s & 511;
    tlist[e*T_ + t] = (t << 13) | (3072 + s); // rows 3072..4095
    wlist[e*T_ + t] = 1.0f;
  }
}

// ---------------- x -> f16 prep ----------------------------------------
__global__ __launch_bounds__(256) void xh_prep_k(
    const float* __restrict__ x, _Float16* __restrict__ xh)
{
  int i = blockIdx.x*256 + threadIdx.x;       // float4 index
  float4 v = ((const float4*)x)[i];
  h4v o = { (_Float16)v.x, (_Float16)v.y, (_Float16)v.z, (_Float16)v.w };
  *(h4v*)(xh + (size_t)i*4) = o;
}

// ---- expert-block descriptor: eb<64 -> routed; eb>=64 -> shared slice ---
__device__ __forceinline__ void eb_decode(int eb, const int* cnt,
                                          int& e, int& lo, int& hi) {
  if (eb < E_) { e = eb; lo = 0; hi = cnt[e]; }
  else { int q = (eb - E_) & 7; e = E_ + ((eb - E_) >> 3); lo = q*64; hi = lo + 64; }
}

// two int4 (8 int32 weights) -> f16 fragment with scale folded
__device__ __forceinline__ h8 cvt8(int4 a, int4 b, float s) {
  union { _Float16 f[8]; h8 v; } t;
  t.f[0]=(_Float16)((float)a.x*s); t.f[1]=(_Float16)((float)a.y*s);
  t.f[2]=(_Float16)((float)a.z*s); t.f[3]=(_Float16)((float)a.w*s);
  t.f[4]=(_Float16)((float)b.x*s); t.f[5]=(_Float16)((float)b.y*s);
  t.f[6]=(_Float16)((float)b.z*s); t.f[7]=(_Float16)((float)b.w*s);
  return t.v;
}

// ---------------- gate+up MFMA: hmid[row, ic*64..+64) -------------------
// 512-thread blocks (8 waves = 4 token-subtiles x 2 i-halves), grid 8x80,
// launch_bounds(512,6) -> 3 blocks/CU = 24 waves/CU resident (BW scales
// with waves: r3 evidence). Tile = 64 tok x 64 i x {g,u}, K-step 32.
// W reg-staged (2 int4/thr/step) -> cvt+scale once -> ds_write_b128 into
// stride-80B rows (16x5: conflict-free b128 r/w). 3-deep W ring, 4-deep A
// ring, 1 barrier/step, counted vmcnt (positional, incl. epilogue stores).
#define NKT_G 32

#define GU_STEP(KT, WN)                                                       \
  do {                                                                        \
    asm volatile("s_waitcnt vmcnt(" #WN ") lgkmcnt(0)" ::: "memory");         \
    __builtin_amdgcn_sched_barrier(0);                                        \
    __builtin_amdgcn_s_barrier();                                             \
    __builtin_amdgcn_sched_barrier(0);                                        \
    if ((KT) + 1 < NKT_G)                                                     \
      *(h8*)(wdst + (((KT)+1)&1)*5120) =                                      \
          cvt8(Wr[((KT)+1)%3][0], Wr[((KT)+1)%3][1], sv[((KT)+1)>>2]);        \
    if ((KT) + 3 < NKT_G) {                                                   \
      Wr[((KT)+3)%3][0] = *(const int4*)(wsrc + ((KT)+3)*32);                 \
      Wr[((KT)+3)%3][1] = *(const int4*)(wsrc + ((KT)+3)*32 + 4);             \
    }                                                                         \
    {                                                                         \
      const _Float16* tb = lds0 + ((KT)&1)*5120;                              \
      h8 bg0 = *(const h8*)(tb + ro0);                                        \
      h8 bg1 = *(const h8*)(tb + ro1);                                        \
      h8 bu0 = *(const h8*)(tb + 2560 + ro0);                                 \
      h8 bu1 = *(const h8*)(tb + 2560 + ro1);                                 \
      accg0 = __builtin_amdgcn_mfma_f32_16x16x32_f16(Ar[(KT)%4], bg0, accg0, 0,0,0); \
      accg1 = __builtin_amdgcn_mfma_f32_16x16x32_f16(Ar[(KT)%4], bg1, accg1, 0,0,0); \
      accu0 = __builtin_amdgcn_mfma_f32_16x16x32_f16(Ar[(KT)%4], bu0, accu0, 0,0,0); \
      accu1 = __builtin_amdgcn_mfma_f32_16x16x32_f16(Ar[(KT)%4], bu1, accu1, 0,0,0); \
    }                                                                         \
    if ((KT) + 3 < NKT_G)                                                     \
      Ar[((KT)+3)%4] = *(const h8*)(ax + ((KT)+3)*32);                        \
  } while (0)

__global__ __launch_bounds__(512, 6) void gateup_k(
    const _Float16* __restrict__ xh,
    const int* __restrict__ wg, const float* __restrict__ sg,
    const int* __restrict__ wu, const float* __restrict__ su,
    const int* __restrict__ shwg, const float* __restrict__ shsg,
    const int* __restrict__ shwu, const float* __restrict__ shsu,
    const int* __restrict__ cnt, const int* __restrict__ tlist,
    const float* __restrict__ wlist,
    _Float16* __restrict__ hmid)
{
  const int ic = blockIdx.x;                  // i-chunk of 64 (0..7)
  const int eb = blockIdx.y;
  int e, lo, hi;
  eb_decode(eb, cnt, e, lo, hi);
  if (hi <= lo) return;

  const int tid  = threadIdx.x;
  const int lane = tid & 63;
  const int wv   = tid >> 6;                  // 0..7
  const int mr   = lane & 15;
  const int quad = lane >> 4;
  const int wm   = wv & 3;                    // token subtile
  const int wn   = wv >> 2;                   // i half (32 cols)

  const int *wgb, *wub; const float *sgp, *sup; int sib;
  if (e < E_) {
    wgb = wg + (size_t)e*I_*H_;  wub = wu + (size_t)e*I_*H_;
    sgp = sg + e*32;  sup = su + e*32;  sib = ic >> 1;
  } else {
    int hf = e - E_;
    wgb = shwg + (size_t)hf*512*H_;  wub = shwu + (size_t)hf*512*H_;
    sgp = shsg;  sup = shsu;  sib = hf*4 + (ic >> 1);
  }

  // staging role: threads 0..255 stage gate, 256..511 stage up
  const int smat = tid >> 8;
  const int sr   = (tid >> 2) & 63;           // tile row
  const int sseg = tid & 3;                   // 8-int segment of 32-int step
  const int* wsrc = (smat ? wub : wgb) + (size_t)(ic*64 + sr)*H_ + sseg*8;
  const float* ssc = (smat ? sup : sgp) + sib*8;
  float sv[8];
  #pragma unroll
  for (int b = 0; b < 8; b++) sv[b] = ssc[b];

  __shared__ _Float16 wlds[2*2*64*40];        // [buf][mat][row][40] 20.5KB
  __shared__ int stok[64]; __shared__ int srw[64]; __shared__ float swt[64];
  _Float16* lds0 = wlds;
  _Float16* wdst = wlds + smat*2560 + sr*40 + sseg*8;
  const int ro0 = (wn*32 + mr)*40 + quad*8;
  const int ro1 = ro0 + 16*40;

  int4 Wr[3][2];
  h8   Ar[4];

  for (int base = lo; base < hi; base += 64) {
    __syncthreads();
    if (tid < 64) {
      int slot = base + tid;
      if (slot < hi) {
        int ent = tlist[e*T_ + slot];
        stok[tid] = ent >> 13; srw[tid] = ent & 8191; swt[tid] = wlist[e*T_ + slot];
      } else { stok[tid] = -1; srw[tid] = 0; swt[tid] = 0.f; }
    }
    __syncthreads();

    int tk = stok[wm*16 + mr]; if (tk < 0) tk = 0;
    const _Float16* ax = xh + (size_t)tk*H_ + quad*8;

    f4 accg0 = (f4){0.f,0.f,0.f,0.f}, accg1 = accg0, accu0 = accg0, accu1 = accg0;

    // prologue: W0 A0 W1 A1 W2 A2 (9 vm loads), wait W0, write buf0
    Wr[0][0] = *(const int4*)(wsrc);      Wr[0][1] = *(const int4*)(wsrc + 4);
    Ar[0]    = *(const h8*)(ax);
    Wr[1][0] = *(const int4*)(wsrc + 32); Wr[1][1] = *(const int4*)(wsrc + 36);
    Ar[1]    = *(const h8*)(ax + 32);
    Wr[2][0] = *(const int4*)(wsrc + 64); Wr[2][1] = *(const int4*)(wsrc + 68);
    Ar[2]    = *(const h8*)(ax + 64);
    asm volatile("s_waitcnt vmcnt(7)" ::: "memory");
    __builtin_amdgcn_sched_barrier(0);
    *(h8*)(wdst) = cvt8(Wr[0][0], Wr[0][1], sv[0]);

    GU_STEP(0,4);  GU_STEP(1,4);  GU_STEP(2,4);  GU_STEP(3,4);
    GU_STEP(4,4);  GU_STEP(5,4);  GU_STEP(6,4);  GU_STEP(7,4);
    GU_STEP(8,4);  GU_STEP(9,4);  GU_STEP(10,4); GU_STEP(11,4);
    GU_STEP(12,4); GU_STEP(13,4); GU_STEP(14,4); GU_STEP(15,4);
    GU_STEP(16,4); GU_STEP(17,4); GU_STEP(18,4); GU_STEP(19,4);
    GU_STEP(20,4); GU_STEP(21,4); GU_STEP(22,4); GU_STEP(23,4);
    GU_STEP(24,4); GU_STEP(25,4); GU_STEP(26,4); GU_STEP(27,4);
    GU_STEP(28,4); GU_STEP(29,4); GU_STEP(30,1); GU_STEP(31,0);

    // epilogue: silu(g)*u*w -> hmid  (C/D: col=mr (i), row=quad*4+r (tok))
    const int icol = ic*64 + wn*32 + mr;
    #pragma unroll
    for (int r = 0; r < 4; r++) {
      int sl = wm*16 + quad*4 + r;
      if (stok[sl] >= 0) {
        float wt = swt[sl];
        float g0 = accg0[r];
        float m0 = g0 / (1.f + expf(-g0)) * accu0[r] * wt;
        float g1 = accg1[r];
        float m1 = g1 / (1.f + expf(-g1)) * accu1[r] * wt;
        _Float16* hp = hmid + (size_t)srw[sl]*I_ + icol;
        hp[0]  = (_Float16)m0;
        hp[16] = (_Float16)m1;
      }
    }
  }
}
#undef GU_STEP

// ---------------- down MFMA: scr[t*8+rank, hc*64..+64) = hmid @ Wd ------
// 256-thread blocks, 64 h-cols/block, grid 16x80 = 1280 -> 5 blocks/CU =
// 20 waves/CU. Wd staged via coalesced 256B row segments + in-register 4x2
// transpose -> stride-80B LDS [h][i] -> contiguous b128 B-frags. Same
// ring/vmcnt schedule as gateup. No atomics: scratch + combine.
#define NKT_D 16

#define DN_LDW(S, KT)                                                         \
  do {                                                                        \
    Wr[S][0] = *(const int2*)(dsrc + (size_t)((KT)*32 + 0)*H_);               \
    Wr[S][1] = *(const int2*)(dsrc + (size_t)((KT)*32 + 1)*H_);               \
    Wr[S][2] = *(const int2*)(dsrc + (size_t)((KT)*32 + 2)*H_);               \
    Wr[S][3] = *(const int2*)(dsrc + (size_t)((KT)*32 + 3)*H_);               \
  } while (0)

#define DN_WRITE(S, BUF, SC)                                                  \
  do {                                                                        \
    union { _Float16 f[4]; h4v v; } v0, v1;                                   \
    v0.f[0]=(_Float16)((float)Wr[S][0].x*(SC)); v0.f[1]=(_Float16)((float)Wr[S][1].x*(SC)); \
    v0.f[2]=(_Float16)((float)Wr[S][2].x*(SC)); v0.f[3]=(_Float16)((float)Wr[S][3].x*(SC)); \
    v1.f[0]=(_Float16)((float)Wr[S][0].y*(SC)); v1.f[1]=(_Float16)((float)Wr[S][1].y*(SC)); \
    v1.f[2]=(_Float16)((float)Wr[S][2].y*(SC)); v1.f[3]=(_Float16)((float)Wr[S][3].y*(SC)); \
    *(h4v*)(ddst0 + (BUF)*2560)      = v0.v;                                  \
    *(h4v*)(ddst0 + (BUF)*2560 + 40) = v1.v;                                  \
  } while (0)

#define DN_STEP(KT, WN)                                                       \
  do {                                                                        \
    asm volatile("s_waitcnt vmcnt(" #WN ") lgkmcnt(0)" ::: "memory");         \
    __builtin_amdgcn_sched_barrier(0);                                        \
    __builtin_amdgcn_s_barrier();                                             \
    __builtin_amdgcn_sched_barrier(0);                                        \
    if ((KT) + 1 < NKT_D) DN_WRITE(((KT)+1)%3, ((KT)+1)&1, scd[((KT)+1)>>2]); \
    if ((KT) + 3 < NKT_D) DN_LDW(((KT)+3)%3, (KT)+3);                         \
    {                                                                         \
      const _Float16* tb = lds0 + ((KT)&1)*2560;                              \
      h8 b0 = *(const h8*)(tb + ro0);                                         \
      h8 b1 = *(const h8*)(tb + ro1);                                         \
      h8 b2 = *(const h8*)(tb + ro2);                                         \
      h8 b3 = *(const h8*)(tb + ro3);                                         \
      tot0 = __builtin_amdgcn_mfma_f32_16x16x32_f16(Ar[(KT)%4], b0, tot0, 0,0,0); \
      tot1 = __builtin_amdgcn_mfma_f32_16x16x32_f16(Ar[(KT)%4], b1, tot1, 0,0,0); \
      tot2 = __builtin_amdgcn_mfma_f32_16x16x32_f16(Ar[(KT)%4], b2, tot2, 0,0,0); \
      tot3 = __builtin_amdgcn_mfma_f32_16x16x32_f16(Ar[(KT)%4], b3, tot3, 0,0,0); \
    }                                                                         \
    if ((KT) + 3 < NKT_D)                                                     \
      Ar[((KT)+3)%4] = *(const h8*)(ap + ((KT)+3)*32);                        \
  } while (0)

__global__ __launch_bounds__(256, 6) void down_k(
    const int* __restrict__ wd, const float* __restrict__ sd,
    const int* __restrict__ shwd, const float* __restrict__ shsd,
    const int* __restrict__ cnt, const int* __restrict__ tlist,
    const _Float16* __restrict__ hmid, float* __restrict__ scr)
{
  const int hc = blockIdx.x;                  // h-chunk of 64 (0..15)
  const int eb = blockIdx.y;
  int e, lo, hi;
  eb_decode(eb, cnt, e, lo, hi);
  if (hi <= lo) return;

  const int tid  = threadIdx.x;
  const int lane = tid & 63;
  const int wv   = tid >> 6;                  // token subtile
  const int mr   = lane & 15;
  const int quad = lane >> 4;

  const int* wb; const float* sdp; int sib0;
  if (e < E_) { wb = wd + (size_t)e*I_*H_;        sdp = sd + e*32;  sib0 = 0; }
  else { int hf = e - E_; wb = shwd + (size_t)hf*512*H_; sdp = shsd; sib0 = hf*4; }
  float scd[4];
  #pragma unroll
  for (int ib = 0; ib < 4; ib++) scd[ib] = sdp[(sib0+ib)*8 + (hc >> 1)];

  // staging: ig = tid>>5 (4-row group), hp = tid&31 (2 h-cols)
  const int ig = tid >> 5;
  const int hp = tid & 31;
  const int* dsrc = wb + (size_t)(ig*4)*H_ + hc*64 + hp*2;

  __shared__ _Float16 wlds[2*64*40];          // [buf][h][40] 10.25KB
  __shared__ int stok[64]; __shared__ int srw[64];
  _Float16* lds0  = wlds;
  _Float16* ddst0 = wlds + (hp*2)*40 + ig*4;
  const int ro0 = (     mr)*40 + quad*8;
  const int ro1 = (16 + mr)*40 + quad*8;
  const int ro2 = (32 + mr)*40 + quad*8;
  const int ro3 = (48 + mr)*40 + quad*8;

  int2 Wr[3][4];
  h8   Ar[4];

  for (int base = lo; base < hi; base += 64) {
    __syncthreads();
    if (tid < 64) {
      int slot = base + tid;
      if (slot < hi) {
        int ent = tlist[e*T_ + slot];
        stok[tid] = ent >> 13; srw[tid] = ent & 8191;
      } else { stok[tid] = -1; srw[tid] = 0; }
    }
    __syncthreads();

    const _Float16* ap = hmid + (size_t)srw[wv*16 + mr]*I_ + quad*8;

    f4 tot0 = (f4){0.f,0.f,0.f,0.f}, tot1 = tot0, tot2 = tot0, tot3 = tot0;

    // prologue: W0(4) A0 W1(4) A1 W2(4) A2 (14 loads), wait W0, write buf0
    DN_LDW(0, 0); Ar[0] = *(const h8*)(ap);
    DN_LDW(1, 1); Ar[1] = *(const h8*)(ap + 32);
    DN_LDW(2, 2); Ar[2] = *(const h8*)(ap + 64);
    asm volatile("s_waitcnt vmcnt(10)" ::: "memory");
    __builtin_amdgcn_sched_barrier(0);
    DN_WRITE(0, 0, scd[0]);

    DN_STEP(0,6);  DN_STEP(1,6);  DN_STEP(2,6);  DN_STEP(3,6);
    DN_STEP(4,6);  DN_STEP(5,6);  DN_STEP(6,6);  DN_STEP(7,6);
    DN_STEP(8,6);  DN_STEP(9,6);  DN_STEP(10,6); DN_STEP(11,6);
    DN_STEP(12,6); DN_STEP(13,6); DN_STEP(14,1); DN_STEP(15,0);

    // epilogue: exactly-once stores to scr[(t*8+rank)][hcol]
    #pragma unroll
    for (int r = 0; r < 4; r++) {
      int sl = wv*16 + quad*4 + r;
      if (stok[sl] >= 0) {
        int t  = stok[sl];
        int sr = srw[sl];
        int rank = (sr < 3072) ? (sr - t*6) : (6 + ((sr - 3072) >> 9));
        float* dst = scr + (size_t)(t*8 + rank)*H_ + hc*64 + mr;
        dst[0]  = tot0[r];
        dst[16] = tot1[r];
        dst[32] = tot2[r];
        dst[48] = tot3[r];
      }
    }
  }
}
#undef DN_STEP
#undef DN_WRITE
#undef DN_LDW

// ---------------- combine: out[t,h] = sum_r scratch[t*8+r, h] -----------
__global__ __launch_bounds__(256) void combine_k(
    const float* __restrict__ scr, float* __restrict__ out)
{
  int i = blockIdx.x*256 + threadIdx.x;       // float4 index over T*H/4
  int t = i >> 8;                             // 256 float4 per token row
  int c = i & 255;
  const float4* base = (const float4*)(scr + (size_t)t*8*H_) + c;
  float4 s = base[0];
  #pragma unroll
  for (int r = 1; r < 8; r++) {
    float4 v = base[(size_t)r*(H_/4)];
    s.x += v.x; s.y += v.y; s.z += v.z; s.w += v.w;
  }
  ((float4*)out)[i] = s;
}

// ---------------- launch ----------------
extern "C" void kernel_launch(void* const* d_in, const int* in_sizes, int n_in,
                              void* d_out, int out_size, void* d_ws, size_t ws_size,
                              hipStream_t stream) {
  (void)in_sizes; (void)n_in; (void)ws_size; (void)out_size;
  const float* x    = (const float*)d_in[0];
  const float* gw   = (const float*)d_in[1];
  const int*   wg   = (const int*  )d_in[2];
  const float* sg   = (const float*)d_in[3];
  const int*   wu   = (const int*  )d_in[4];
  const float* su   = (const float*)d_in[5];
  const int*   wd   = (const int*  )d_in[6];
  const float* sd   = (const float*)d_in[7];
  const int*   shwg = (const int*  )d_in[8];
  const float* shsg = (const float*)d_in[9];
  const int*   shwu = (const int*  )d_in[10];
  const float* shsu = (const float*)d_in[11];
  const int*   shwd = (const int*  )d_in[12];
  const float* shsd = (const float*)d_in[13];
  float* out = (float*)d_out;

  char* ws = (char*)d_ws;
  int*      cnt   = (int*     ) ws;                                   // 66 ints
  int*      tlist = (int*     )(ws + 1024);                           // 66*512
  float*    wlist = (float*   )(ws + 1024 + 66*T_*4);                 // 66*512
  _Float16* hmid  = (_Float16*)(ws + 1024 + 2*66*T_*4);               // 4096*512 f16
  _Float16* xh    = (_Float16*)(ws + 1024 + 2*66*T_*4 + 4096*I_*2);   // 512*1024 f16
  float*    scr   = (float*   )(ws + 1024 + 2*66*T_*4 + 4096*I_*2 + T_*H_*2); // 4096*1024 f32

  hipMemsetAsync(cnt, 0, 1024, stream);
  xh_prep_k<<<T_*H_/1024, 256, 0, stream>>>(x, xh);
  router_k<<<T_, 64, 0, stream>>>(x, gw, cnt, tlist, wlist);
  pseudo_init_k<<<4, 256, 0, stream>>>(cnt, tlist, wlist);
  gateup_k<<<dim3(8, EB_), 512, 0, stream>>>(xh, wg, sg, wu, su,
                                             shwg, shsg, shwu, shsu,
                                             cnt, tlist, wlist, hmid);
  down_k<<<dim3(16, EB_), 256, 0, stream>>>(wd, sd, shwd, shsd,
                                            cnt, tlist, hmid, scr);
  combine_k<<<T_*H_/1024, 256, 0, stream>>>(scr, out);
}

// Round 5
// 538.318 us; speedup vs baseline: 1.1023x; 1.0353x over previous
//
#include <hip/hip_runtime.h>
#include <math.h>
#include <stdint.h>

#define T_   512
#define H_   1024
#define I_   512
#define E_   64
#define K_   6
#define G_   8
#define TG_  3
#define EB_  80      // 64 routed + 16 shared-expert (half x token-eighth) blocks

typedef _Float16 h8 __attribute__((ext_vector_type(8)));
typedef _Float16 h4v __attribute__((ext_vector_type(4)));
typedef float    f4 __attribute__((ext_vector_type(4)));

// ------- router + xh-prep + pseudo-init + wrow table (fused) ------------
__global__ __launch_bounds__(64) void router_k(
    const float* __restrict__ x, const float* __restrict__ gw,
    int* __restrict__ cnt, int* __restrict__ tlist,
    float* __restrict__ wrow, _Float16* __restrict__ xh)
{
  const int t   = blockIdx.x;
  const int tid = threadIdx.x;
  __shared__ float sx[H_];
  __shared__ float sc[E_];

  for (int h4 = tid; h4 < H_/4; h4 += 64)
    ((float4*)sx)[h4] = ((const float4*)(x + (size_t)t*H_))[h4];
  __syncthreads();

  // fused: x -> f16 (xh)
  for (int h4 = tid; h4 < H_/4; h4 += 64) {
    float4 v = ((const float4*)sx)[h4];
    h4v o = { (_Float16)v.x, (_Float16)v.y, (_Float16)v.z, (_Float16)v.w };
    *(h4v*)(xh + (size_t)t*H_ + h4*4) = o;
  }
  // fused: pseudo-expert lists + shared wrow (blocks 0..15)
  if (t < 16) {
    int s  = t*64 + tid;                      // 0..1023
    int e  = 64 + (s >> 9);
    int tt = s & 511;
    tlist[e*T_ + tt] = (tt << 13) | (3072 + s);
    wrow[3072 + s] = 1.0f;
    if (s == 0) { cnt[64] = T_; cnt[65] = T_; }
  }

  const float* wr = gw + (size_t)tid * H_;
  float acc = 0.f;
  for (int h = 0; h < H_; h += 4) {
    float4 xv = *(const float4*)(sx + h);
    float4 wv = *(const float4*)(wr + h);
    acc = fmaf(xv.x, wv.x, acc); acc = fmaf(xv.y, wv.y, acc);
    acc = fmaf(xv.z, wv.z, acc); acc = fmaf(xv.w, wv.w, acc);
  }
  sc[tid] = 1.f / (1.f + expf(-acc));
  __syncthreads();

  if (tid == 0) {
    float gs[G_];
    #pragma unroll
    for (int g = 0; g < G_; g++) {
      float m = sc[g*8];
      #pragma unroll
      for (int j = 1; j < 8; j++) m = fmaxf(m, sc[g*8+j]);
      gs[g] = m;
    }
    unsigned gp = 0;
    for (int r = 0; r < TG_; r++) {
      int best = 0; float bv = -1e30f;
      for (int g = 0; g < G_; g++)
        if (!((gp >> g) & 1) && gs[g] > bv) { bv = gs[g]; best = g; }
      gp |= 1u << best;
    }
    int   eidx[K_]; float ew[K_];
    unsigned long long em = 0ull;
    float wsum = 0.f;
    for (int r = 0; r < K_; r++) {
      int best = 0; float bv = -1e30f;
      for (int e = 0; e < E_; e++) {
        if (!((gp >> (e >> 3)) & 1)) continue;
        if ((em >> e) & 1ull) continue;
        if (sc[e] > bv) { bv = sc[e]; best = e; }
      }
      em |= 1ull << best; eidx[r] = best; ew[r] = bv; wsum += bv;
    }
    const float inv = 2.5f / (wsum + 1e-20f);
    for (int r = 0; r < K_; r++) {
      int e = eidx[r];
      int pos = atomicAdd(&cnt[e], 1);
      tlist[e*T_ + pos] = (t << 13) | (t*K_ + r);   // row = t*6+rank
      wrow[t*K_ + r] = ew[r] * inv;
    }
  }
}

// ---- expert-block descriptor: eb<64 -> routed; eb>=64 -> shared slice ---
__device__ __forceinline__ void eb_decode(int eb, const int* cnt,
                                          int& e, int& lo, int& hi) {
  if (eb < E_) { e = eb; lo = 0; hi = cnt[e]; }
  else { int q = (eb - E_) & 7; e = E_ + ((eb - E_) >> 3); lo = q*64; hi = lo + 64; }
}

// two int4 (8 int32 weights) -> f16 fragment with scale folded
__device__ __forceinline__ h8 cvt8(int4 a, int4 b, float s) {
  union { _Float16 f[8]; h8 v; } t;
  t.f[0]=(_Float16)((float)a.x*s); t.f[1]=(_Float16)((float)a.y*s);
  t.f[2]=(_Float16)((float)a.z*s); t.f[3]=(_Float16)((float)a.w*s);
  t.f[4]=(_Float16)((float)b.x*s); t.f[5]=(_Float16)((float)b.y*s);
  t.f[6]=(_Float16)((float)b.z*s); t.f[7]=(_Float16)((float)b.w*s);
  return t.v;
}

// ---------------- gate+up MFMA, K-split: gpart[kc][mat][row][i] ---------
// Grid 16x80 (ic 0..7, kc 0..1) x 512 thr = 10240 waves = 40/CU available;
// launch_bounds(512,8) -> cap 32 waves/CU (4 blk). Tile 64 tok x 64 i x
// {g,u}, K-half = 512, K-step 32. r4-verified ring schedule + stride-80B
// LDS rows; partial f32 sums out (silu+wt applied in gu_fin).
#define NKT_G 16

#define GU_STEP(KT, WN)                                                       \
  do {                                                                        \
    asm volatile("s_waitcnt vmcnt(" #WN ") lgkmcnt(0)" ::: "memory");         \
    __builtin_amdgcn_sched_barrier(0);                                        \
    __builtin_amdgcn_s_barrier();                                             \
    __builtin_amdgcn_sched_barrier(0);                                        \
    if ((KT) + 1 < NKT_G)                                                     \
      *(h8*)(wdst + (((KT)+1)&1)*5120) =                                      \
          cvt8(Wr[((KT)+1)%3][0], Wr[((KT)+1)%3][1], sv[(((KT)+1)>>2)&3]);    \
    if ((KT) + 3 < NKT_G) {                                                   \
      Wr[((KT)+3)%3][0] = *(const int4*)(wsrc + ((KT)+3)*32);                 \
      Wr[((KT)+3)%3][1] = *(const int4*)(wsrc + ((KT)+3)*32 + 4);             \
    }                                                                         \
    {                                                                         \
      const _Float16* tb = lds0 + ((KT)&1)*5120;                              \
      h8 bg0 = *(const h8*)(tb + ro0);                                        \
      h8 bg1 = *(const h8*)(tb + ro1);                                        \
      h8 bu0 = *(const h8*)(tb + 2560 + ro0);                                 \
      h8 bu1 = *(const h8*)(tb + 2560 + ro1);                                 \
      accg0 = __builtin_amdgcn_mfma_f32_16x16x32_f16(Ar[(KT)%4], bg0, accg0, 0,0,0); \
      accg1 = __builtin_amdgcn_mfma_f32_16x16x32_f16(Ar[(KT)%4], bg1, accg1, 0,0,0); \
      accu0 = __builtin_amdgcn_mfma_f32_16x16x32_f16(Ar[(KT)%4], bu0, accu0, 0,0,0); \
      accu1 = __builtin_amdgcn_mfma_f32_16x16x32_f16(Ar[(KT)%4], bu1, accu1, 0,0,0); \
    }                                                                         \
    if ((KT) + 3 < NKT_G)                                                     \
      Ar[((KT)+3)%4] = *(const h8*)(ax + ((KT)+3)*32);                        \
  } while (0)

__global__ __launch_bounds__(512, 8) void gateup_k(
    const _Float16* __restrict__ xh,
    const int* __restrict__ wg, const float* __restrict__ sg,
    const int* __restrict__ wu, const float* __restrict__ su,
    const int* __restrict__ shwg, const float* __restrict__ shsg,
    const int* __restrict__ shwu, const float* __restrict__ shsu,
    const int* __restrict__ cnt, const int* __restrict__ tlist,
    float* __restrict__ gpart)
{
  const int bx = blockIdx.x;
  const int ic = bx & 7;                      // i-chunk of 64
  const int kc = bx >> 3;                     // K half (0,1)
  const int eb = blockIdx.y;
  int e, lo, hi;
  eb_decode(eb, cnt, e, lo, hi);
  if (hi <= lo) return;

  const int tid  = threadIdx.x;
  const int lane = tid & 63;
  const int wv   = tid >> 6;                  // 0..7
  const int mr   = lane & 15;
  const int quad = lane >> 4;
  const int wm   = wv & 3;                    // token subtile
  const int wn   = wv >> 2;                   // i half (32 cols)

  const int *wgb, *wub; const float *sgp, *sup; int sib;
  if (e < E_) {
    wgb = wg + (size_t)e*I_*H_;  wub = wu + (size_t)e*I_*H_;
    sgp = sg + e*32;  sup = su + e*32;  sib = ic >> 1;
  } else {
    int hf = e - E_;
    wgb = shwg + (size_t)hf*512*H_;  wub = shwu + (size_t)hf*512*H_;
    sgp = shsg;  sup = shsu;  sib = hf*4 + (ic >> 1);
  }

  // staging role: threads 0..255 stage gate, 256..511 stage up
  const int smat = tid >> 8;
  const int sr   = (tid >> 2) & 63;           // tile row
  const int sseg = tid & 3;                   // 8-int segment of 32-int step
  const int* wsrc = (smat ? wub : wgb) + (size_t)(ic*64 + sr)*H_ + kc*512 + sseg*8;
  const float* ssc = (smat ? sup : sgp) + sib*8 + kc*4;
  float sv[4];
  #pragma unroll
  for (int b = 0; b < 4; b++) sv[b] = ssc[b];

  __shared__ _Float16 wlds[2*2*64*40];        // [buf][mat][row][40] 20.5KB
  __shared__ int stok[64]; __shared__ int srw[64];
  _Float16* lds0 = wlds;
  _Float16* wdst = wlds + smat*2560 + sr*40 + sseg*8;
  const int ro0 = (wn*32 + mr)*40 + quad*8;
  const int ro1 = ro0 + 16*40;

  float* gp = gpart + (size_t)(kc*2 + 0)*4096*512;
  float* up = gpart + (size_t)(kc*2 + 1)*4096*512;

  int4 Wr[3][2];
  h8   Ar[4];

  for (int base = lo; base < hi; base += 64) {
    __syncthreads();
    if (tid < 64) {
      int slot = base + tid;
      if (slot < hi) {
        int ent = tlist[e*T_ + slot];
        stok[tid] = ent >> 13; srw[tid] = ent & 8191;
      } else { stok[tid] = -1; srw[tid] = 0; }
    }
    __syncthreads();

    int tk = stok[wm*16 + mr]; if (tk < 0) tk = 0;
    const _Float16* ax = xh + (size_t)tk*H_ + kc*512 + quad*8;

    f4 accg0 = (f4){0.f,0.f,0.f,0.f}, accg1 = accg0, accu0 = accg0, accu1 = accg0;

    // prologue: W0 A0 W1 A1 W2 A2 (9 vm loads), wait W0, write buf0
    Wr[0][0] = *(const int4*)(wsrc);      Wr[0][1] = *(const int4*)(wsrc + 4);
    Ar[0]    = *(const h8*)(ax);
    Wr[1][0] = *(const int4*)(wsrc + 32); Wr[1][1] = *(const int4*)(wsrc + 36);
    Ar[1]    = *(const h8*)(ax + 32);
    Wr[2][0] = *(const int4*)(wsrc + 64); Wr[2][1] = *(const int4*)(wsrc + 68);
    Ar[2]    = *(const h8*)(ax + 64);
    asm volatile("s_waitcnt vmcnt(7)" ::: "memory");
    __builtin_amdgcn_sched_barrier(0);
    *(h8*)(wdst) = cvt8(Wr[0][0], Wr[0][1], sv[0]);

    GU_STEP(0,4);  GU_STEP(1,4);  GU_STEP(2,4);  GU_STEP(3,4);
    GU_STEP(4,4);  GU_STEP(5,4);  GU_STEP(6,4);  GU_STEP(7,4);
    GU_STEP(8,4);  GU_STEP(9,4);  GU_STEP(10,4); GU_STEP(11,4);
    GU_STEP(12,4); GU_STEP(13,4); GU_STEP(14,1); GU_STEP(15,0);

    // epilogue: f32 partial g,u -> gpart  (C/D: col=mr (i), row=quad*4+r)
    const int icol = ic*64 + wn*32 + mr;
    #pragma unroll
    for (int r = 0; r < 4; r++) {
      int sl = wm*16 + quad*4 + r;
      if (stok[sl] >= 0) {
        size_t ro = (size_t)srw[sl]*512 + icol;
        gp[ro]      = accg0[r];
        gp[ro + 16] = accg1[r];
        up[ro]      = accu0[r];
        up[ro + 16] = accu1[r];
      }
    }
  }
}
#undef GU_STEP

// ---------------- gu_fin: hmid = silu(g0+g1)*(u0+u1)*wrow ---------------
__global__ __launch_bounds__(256) void gu_fin_k(
    const float* __restrict__ gpart, const float* __restrict__ wrow,
    _Float16* __restrict__ hmid)
{
  int i = blockIdx.x*256 + threadIdx.x;       // float4 idx over 4096*512/4
  int row = i >> 7;
  const float4* g0 = (const float4*)(gpart)                        + i;
  const float4* u0 = (const float4*)(gpart + (size_t)1*4096*512)   + i;
  const float4* g1 = (const float4*)(gpart + (size_t)2*4096*512)   + i;
  const float4* u1 = (const float4*)(gpart + (size_t)3*4096*512)   + i;
  float4 ga = *g0, gb = *g1, ua = *u0, ub = *u1;
  float w = wrow[row];
  union { _Float16 f[4]; h4v v; } o;
  #pragma unroll
  for (int j = 0; j < 4; j++) {
    float g = (&ga.x)[j] + (&gb.x)[j];
    float u = (&ua.x)[j] + (&ub.x)[j];
    o.f[j] = (_Float16)(g / (1.f + expf(-g)) * u * w);
  }
  *(h4v*)(hmid + (size_t)i*4) = o.v;
}

// ---------------- down MFMA, K-split: scr[kc][t*8+rank][h] --------------
// Grid 32x80 (hc 0..15, kc 0..1) x 256 thr = 10240 waves = 40/CU available
// (cap 24 at launch_bounds(256,6), VGPR-safe). Tile 64 tok x 64 h,
// K-half 256, K-step 32. r4-verified transpose-stage + ring schedule.
#define NKT_D 8

#define DN_LDW(S, KT)                                                         \
  do {                                                                        \
    Wr[S][0] = *(const int2*)(dsrc + (size_t)((KT)*32 + 0)*H_);               \
    Wr[S][1] = *(const int2*)(dsrc + (size_t)((KT)*32 + 1)*H_);               \
    Wr[S][2] = *(const int2*)(dsrc + (size_t)((KT)*32 + 2)*H_);               \
    Wr[S][3] = *(const int2*)(dsrc + (size_t)((KT)*32 + 3)*H_);               \
  } while (0)

#define DN_WRITE(S, BUF, SC)                                                  \
  do {                                                                        \
    union { _Float16 f[4]; h4v v; } v0, v1;                                   \
    v0.f[0]=(_Float16)((float)Wr[S][0].x*(SC)); v0.f[1]=(_Float16)((float)Wr[S][1].x*(SC)); \
    v0.f[2]=(_Float16)((float)Wr[S][2].x*(SC)); v0.f[3]=(_Float16)((float)Wr[S][3].x*(SC)); \
    v1.f[0]=(_Float16)((float)Wr[S][0].y*(SC)); v1.f[1]=(_Float16)((float)Wr[S][1].y*(SC)); \
    v1.f[2]=(_Float16)((float)Wr[S][2].y*(SC)); v1.f[3]=(_Float16)((float)Wr[S][3].y*(SC)); \
    *(h4v*)(ddst0 + (BUF)*2560)      = v0.v;                                  \
    *(h4v*)(ddst0 + (BUF)*2560 + 40) = v1.v;                                  \
  } while (0)

#define DN_STEP(KT, WN)                                                       \
  do {                                                                        \
    asm volatile("s_waitcnt vmcnt(" #WN ") lgkmcnt(0)" ::: "memory");         \
    __builtin_amdgcn_sched_barrier(0);                                        \
    __builtin_amdgcn_s_barrier();                                             \
    __builtin_amdgcn_sched_barrier(0);                                        \
    if ((KT) + 1 < NKT_D) DN_WRITE(((KT)+1)%3, ((KT)+1)&1, scd[(((KT)+1)>>2)&1]); \
    if ((KT) + 3 < NKT_D) DN_LDW(((KT)+3)%3, (KT)+3);                         \
    {                                                                         \
      const _Float16* tb = lds0 + ((KT)&1)*2560;                              \
      h8 b0 = *(const h8*)(tb + ro0);                                         \
      h8 b1 = *(const h8*)(tb + ro1);                                         \
      h8 b2 = *(const h8*)(tb + ro2);                                         \
      h8 b3 = *(const h8*)(tb + ro3);                                         \
      tot0 = __builtin_amdgcn_mfma_f32_16x16x32_f16(Ar[(KT)%4], b0, tot0, 0,0,0); \
      tot1 = __builtin_amdgcn_mfma_f32_16x16x32_f16(Ar[(KT)%4], b1, tot1, 0,0,0); \
      tot2 = __builtin_amdgcn_mfma_f32_16x16x32_f16(Ar[(KT)%4], b2, tot2, 0,0,0); \
      tot3 = __builtin_amdgcn_mfma_f32_16x16x32_f16(Ar[(KT)%4], b3, tot3, 0,0,0); \
    }                                                                         \
    if ((KT) + 3 < NKT_D)                                                     \
      Ar[((KT)+3)%4] = *(const h8*)(ap + ((KT)+3)*32);                        \
  } while (0)

__global__ __launch_bounds__(256, 6) void down_k(
    const int* __restrict__ wd, const float* __restrict__ sd,
    const int* __restrict__ shwd, const float* __restrict__ shsd,
    const int* __restrict__ cnt, const int* __restrict__ tlist,
    const _Float16* __restrict__ hmid, float* __restrict__ scr)
{
  const int bx = blockIdx.x;
  const int hc = bx & 15;                     // h-chunk of 64
  const int kc = bx >> 4;                     // K half (0,1) of I
  const int eb = blockIdx.y;
  int e, lo, hi;
  eb_decode(eb, cnt, e, lo, hi);
  if (hi <= lo) return;

  const int tid  = threadIdx.x;
  const int lane = tid & 63;
  const int wv   = tid >> 6;                  // token subtile
  const int mr   = lane & 15;
  const int quad = lane >> 4;

  const int* wb; const float* sdp; int sib0;
  if (e < E_) { wb = wd + (size_t)e*I_*H_;        sdp = sd + e*32;  sib0 = 0; }
  else { int hf = e - E_; wb = shwd + (size_t)hf*512*H_; sdp = shsd; sib0 = hf*4; }
  float scd[2];
  #pragma unroll
  for (int ib = 0; ib < 2; ib++) scd[ib] = sdp[(sib0 + kc*2 + ib)*8 + (hc >> 1)];

  // staging: ig = tid>>5 (4-row group), hp = tid&31 (2 h-cols)
  const int ig = tid >> 5;
  const int hp = tid & 31;
  const int* dsrc = wb + (size_t)(kc*256 + ig*4)*H_ + hc*64 + hp*2;

  __shared__ _Float16 wlds[2*64*40];          // [buf][h][40] 10.25KB
  __shared__ int stok[64]; __shared__ int srw[64];
  _Float16* lds0  = wlds;
  _Float16* ddst0 = wlds + (hp*2)*40 + ig*4;
  const int ro0 = (     mr)*40 + quad*8;
  const int ro1 = (16 + mr)*40 + quad*8;
  const int ro2 = (32 + mr)*40 + quad*8;
  const int ro3 = (48 + mr)*40 + quad*8;

  float* scrk = scr + (size_t)kc*4096*H_;

  int2 Wr[3][4];
  h8   Ar[4];

  for (int base = lo; base < hi; base += 64) {
    __syncthreads();
    if (tid < 64) {
      int slot = base + tid;
      if (slot < hi) {
        int ent = tlist[e*T_ + slot];
        stok[tid] = ent >> 13; srw[tid] = ent & 8191;
      } else { stok[tid] = -1; srw[tid] = 0; }
    }
    __syncthreads();

    const _Float16* ap = hmid + (size_t)srw[wv*16 + mr]*I_ + kc*256 + quad*8;

    f4 tot0 = (f4){0.f,0.f,0.f,0.f}, tot1 = tot0, tot2 = tot0, tot3 = tot0;

    // prologue: W0(4) A0 W1(4) A1 W2(4) A2 (15 loads), wait W0+A0, write
    DN_LDW(0, 0); Ar[0] = *(const h8*)(ap);
    DN_LDW(1, 1); Ar[1] = *(const h8*)(ap + 32);
    DN_LDW(2, 2); Ar[2] = *(const h8*)(ap + 64);
    asm volatile("s_waitcnt vmcnt(10)" ::: "memory");
    __builtin_amdgcn_sched_barrier(0);
    DN_WRITE(0, 0, scd[0]);

    DN_STEP(0,6); DN_STEP(1,6); DN_STEP(2,6); DN_STEP(3,6);
    DN_STEP(4,6); DN_STEP(5,6); DN_STEP(6,1); DN_STEP(7,0);

    // epilogue: exactly-once stores to scr[kc][(t*8+rank)][hcol]
    #pragma unroll
    for (int r = 0; r < 4; r++) {
      int sl = wv*16 + quad*4 + r;
      if (stok[sl] >= 0) {
        int t  = stok[sl];
        int sr = srw[sl];
        int rank = (sr < 3072) ? (sr - t*6) : (6 + ((sr - 3072) >> 9));
        float* dst = scrk + (size_t)(t*8 + rank)*H_ + hc*64 + mr;
        dst[0]  = tot0[r];
        dst[16] = tot1[r];
        dst[32] = tot2[r];
        dst[48] = tot3[r];
      }
    }
  }
}
#undef DN_STEP
#undef DN_WRITE
#undef DN_LDW

// ---------------- dn_fin: out[t,h] = sum_{kc,r} scr[kc][t*8+r][h] -------
__global__ __launch_bounds__(256) void dn_fin_k(
    const float* __restrict__ scr, float* __restrict__ out)
{
  int i = blockIdx.x*256 + threadIdx.x;       // float4 index over T*H/4
  int t = i >> 8;
  int c = i & 255;
  const float4* b0 = (const float4*)(scr)                      + (size_t)t*8*(H_/4) + c;
  const float4* b1 = (const float4*)(scr + (size_t)4096*H_)    + (size_t)t*8*(H_/4) + c;
  float4 s = {0.f, 0.f, 0.f, 0.f};
  #pragma unroll
  for (int r = 0; r < 8; r++) {
    float4 v0 = b0[(size_t)r*(H_/4)];
    float4 v1 = b1[(size_t)r*(H_/4)];
    s.x += v0.x + v1.x; s.y += v0.y + v1.y;
    s.z += v0.z + v1.z; s.w += v0.w + v1.w;
  }
  ((float4*)out)[i] = s;
}

// ---------------- launch ----------------
extern "C" void kernel_launch(void* const* d_in, const int* in_sizes, int n_in,
                              void* d_out, int out_size, void* d_ws, size_t ws_size,
                              hipStream_t stream) {
  (void)in_sizes; (void)n_in; (void)ws_size; (void)out_size;
  const float* x    = (const float*)d_in[0];
  const float* gw   = (const float*)d_in[1];
  const int*   wg   = (const int*  )d_in[2];
  const float* sg   = (const float*)d_in[3];
  const int*   wu   = (const int*  )d_in[4];
  const float* su   = (const float*)d_in[5];
  const int*   wd   = (const int*  )d_in[6];
  const float* sd   = (const float*)d_in[7];
  const int*   shwg = (const int*  )d_in[8];
  const float* shsg = (const float*)d_in[9];
  const int*   shwu = (const int*  )d_in[10];
  const float* shsu = (const float*)d_in[11];
  const int*   shwd = (const int*  )d_in[12];
  const float* shsd = (const float*)d_in[13];
  float* out = (float*)d_out;

  char* ws = (char*)d_ws;
  int*      cnt   = (int*     ) ws;                       // 1 KB
  int*      tlist = (int*     )(ws + 1024);               // 66*512*4 = 132 KB
  float*    wrow  = (float*   )(ws + 136192);             // 4096*4 = 16 KB
  _Float16* hmid  = (_Float16*)(ws + 152576);             // 4096*512*2 = 4 MB
  _Float16* xh    = (_Float16*)(ws + 4346880);            // 512*1024*2 = 1 MB
  float*    big   = (float*   )(ws + 5395456);            // 32 MB (gpart/scr alias)

  hipMemsetAsync(cnt, 0, 1024, stream);
  router_k<<<T_, 64, 0, stream>>>(x, gw, cnt, tlist, wrow, xh);
  gateup_k<<<dim3(16, EB_), 512, 0, stream>>>(xh, wg, sg, wu, su,
                                              shwg, shsg, shwu, shsu,
                                              cnt, tlist, big);
  gu_fin_k<<<2048, 256, 0, stream>>>(big, wrow, hmid);
  down_k<<<dim3(32, EB_), 256, 0, stream>>>(wd, sd, shwd, shsd,
                                            cnt, tlist, hmid, big);
  dn_fin_k<<<512, 256, 0, stream>>>(big, out);
}